// Round 6
// baseline (47.223 us; speedup 1.0000x reference)
//
#include <hip/hip_runtime.h>

// RandomShift (DrQ-style): x[512,9,84,84] f32, shift[512,2] int32 in [0,8].
// out[n,c,i,j] = bilinear tap of zero-padded x at
// (row = j*91/83 + s1 - 4, col = i*91/83 + s0 - 4) in image coords.
//
// v5: 4x4 output tile per thread to cut LDS traffic (the measured wall):
//  - transposed LDS (lds[col*85+row]), staged via float4 loads + 4 writes
//  - per tile: 6 columns x 4 ds_read2_b32; ycol[e] (y-interp) shared
//    across the 4 i's -> 48 LDS dwords / 16 outputs (was 64)
//  - column selection via compare-select weights (static reg indices only):
//    both x-taps of every i provably lie in [cbase, cbase+5]
//  - slot-weight boundary trick (R4) handles all OOB cases in the weights
//  - 448 threads = 7 waves x 63 active lanes = 441 tiles = whole plane

constexpr int HW     = 84;
constexpr int LDSW   = 85;           // gcd(85,32)=1
constexpr int NPLANE = HW * HW;      // 7056
constexpr int NQUADS = NPLANE / 4;   // 1764

typedef float vfloat4 __attribute__((ext_vector_type(4)));

__device__ __forceinline__ int iclamp(int v, int lo, int hi) {
    return v < lo ? lo : (v > hi ? hi : v);
}

__global__ __launch_bounds__(448) void rshift_kernel(
    const float* __restrict__ x,
    const int*   __restrict__ shift,
    float*       __restrict__ out)
{
    __shared__ float lds[HW * LDSW];         // lds[col*LDSW + row] (transposed)

    const int plane = blockIdx.x;            // n*9 + c
    const int n     = plane / 9;
    const float s0  = (float)shift[2 * n];       // along i (columns)
    const float s1  = (float)shift[2 * n + 1];   // along j (rows)
    const float* __restrict__ src = x   + (size_t)plane * NPLANE;
    float*       __restrict__ dst = out + (size_t)plane * NPLANE;
    const int t = threadIdx.x;
    const float R = 91.0f / 83.0f;

    // ---- stage plane into LDS, transposed (float4 loads, 4 writes each) ----
    #pragma unroll
    for (int k = 0; k < 4; ++k) {
        int q = t + k * 448;
        if (q < NQUADS) {
            int row  = q / 21;               // 21 quads per input row
            int col0 = (q - row * 21) * 4;
            vfloat4 v = *reinterpret_cast<const vfloat4*>(src + q * 4);
            int b = col0 * LDSW + row;
            lds[b]            = v.x;
            lds[b + LDSW]     = v.y;
            lds[b + 2 * LDSW] = v.z;
            lds[b + 3 * LDSW] = v.w;
        }
    }

    // ---- per-thread tile coords: lane -> (jq, iq) ----
    const int lane = t & 63;
    const int wv   = t >> 6;             // 0..6
    const int jq   = lane % 21;          // j-quad
    const int iq   = wv * 3 + lane / 21; // 0..20 for lane<63
    const bool active = (lane != 63);

    // y-params per e (slot-weight form; rows read at exact cb)
    float wy0s[4], wy1s[4];
    int   rr[4];
    #pragma unroll
    for (int e = 0; e < 4; ++e) {
        float fy = fmaf((float)(4 * jq + e), R, s1);
        int   y0 = (int)fy;              // fy >= 0
        float w1 = fy - (float)y0;
        float w0 = 1.0f - w1;
        int   t0 = y0 - 4;
        int   cb = iclamp(t0, 0, HW - 2);
        wy0s[e] = (t0 == cb) ? w0 : ((t0 + 1 == cb) ? w1 : 0.0f);
        wy1s[e] = (t0 == cb) ? w1 : ((t0 - 1 == cb) ? w0 : 0.0f);
        rr[e] = cb;
    }

    // x-params per a: slot weights + position within 6-col window
    float wx0s[4], wx1s[4];
    int   pa[4];
    int   cbase = 0;
    #pragma unroll
    for (int a = 0; a < 4; ++a) {
        float fx = fmaf((float)(4 * iq + a), R, s0);
        int   x0 = (int)fx;
        float w1 = fx - (float)x0;
        float w0 = 1.0f - w1;
        int   u0 = x0 - 4;
        int   cb = iclamp(u0, 0, HW - 2);
        if (a == 0) cbase = iclamp(u0, 0, HW - 6);   // window start
        wx0s[a] = (u0 == cb) ? w0 : ((u0 + 1 == cb) ? w1 : 0.0f);
        wx1s[a] = (u0 == cb) ? w1 : ((u0 - 1 == cb) ? w0 : 0.0f);
        pa[a]   = cb - cbase;            // in [0,4]; taps at window cols pa, pa+1
    }

    __syncthreads();

    // ---- compute 4x4 tile: stream 6 columns, share ycol across i ----
    if (active) {
        float acc[4][4];                 // [a][e], static indices only
        #pragma unroll
        for (int a = 0; a < 4; ++a)
            #pragma unroll
            for (int e = 0; e < 4; ++e) acc[a][e] = 0.0f;

        const int base = cbase * LDSW;
        #pragma unroll
        for (int c = 0; c < 6; ++c) {
            const int caddr = base + c * LDSW;
            float yc[4];
            #pragma unroll
            for (int e = 0; e < 4; ++e) {
                float v0 = lds[caddr + rr[e]];       // pair -> ds_read2_b32
                float v1 = lds[caddr + rr[e] + 1];
                yc[e] = wy0s[e] * v0 + wy1s[e] * v1;
            }
            #pragma unroll
            for (int a = 0; a < 4; ++a) {
                float w = (c == pa[a]) ? wx0s[a]
                        : ((c == pa[a] + 1) ? wx1s[a] : 0.0f);
                #pragma unroll
                for (int e = 0; e < 4; ++e)
                    acc[a][e] = fmaf(w, yc[e], acc[a][e]);
            }
        }

        #pragma unroll
        for (int a = 0; a < 4; ++a) {
            vfloat4 o;
            o.x = acc[a][0]; o.y = acc[a][1]; o.z = acc[a][2]; o.w = acc[a][3];
            __builtin_nontemporal_store(
                o, reinterpret_cast<vfloat4*>(
                       dst + (size_t)(4 * iq + a) * HW + 4 * jq));
        }
    }
}

extern "C" void kernel_launch(void* const* d_in, const int* in_sizes, int n_in,
                              void* d_out, int out_size, void* d_ws, size_t ws_size,
                              hipStream_t stream) {
    const float* x     = (const float*)d_in[0];
    const int*   shift = (const int*)d_in[1];
    float*       out   = (float*)d_out;
    const int planes = 512 * 9;   // one block per (n,c) plane
    rshift_kernel<<<planes, 448, 0, stream>>>(x, shift, out);
}

// Round 7
// 44.477 us; speedup vs baseline: 1.0617x; 1.0617x over previous
//
#include <hip/hip_runtime.h>

// RandomShift (DrQ-style): x[512,9,84,84] f32, shift[512,2] int32 in [0,8].
// out[n,c,i,j] = bilinear tap of zero-padded x at
// (row = j*91/83 + s1 - 4, col = i*91/83 + s0 - 4), image coords in [0,84).
//
// v6 = R4 internals (transposed LDS stride 85, slot-weight boundary trick,
// lane = jq + 21*isub, nt float4 stores) + multi-plane pipelining:
//  - 3 planes per block (all 9 c of an n share one shift -> params hoisted,
//    computed once per block); grid = 512*3 = 1536 blocks, 512 threads.
//  - double-buffered LDS (2 x 28.6 KB); per plane: issue next plane's
//    global float4 loads EARLY, compute current plane (loads in flight
//    under compute = T14 async-split), then ds_write staged regs, barrier.
//  - one barrier per plane; HBM read stream never drains serially.

constexpr int HW     = 84;
constexpr int LDSW   = 85;           // gcd(85,32)=1
constexpr int NPLANE = HW * HW;      // 7056
constexpr int NQUADS = NPLANE / 4;   // 1764 = 3*512 + 228

typedef float vfloat4 __attribute__((ext_vector_type(4)));

__device__ __forceinline__ int iclamp(int v, int lo, int hi) {
    return v < lo ? lo : (v > hi ? hi : v);
}

__global__ __launch_bounds__(512) void rshift_kernel(
    const float* __restrict__ x,
    const int*   __restrict__ shift,
    float*       __restrict__ out)
{
    __shared__ float lds[2][HW * LDSW];

    const int blk = blockIdx.x;            // 0..1535
    const int n   = blk / 3;
    const int c0  = (blk - n * 3) * 3;     // planes c0..c0+2 of image n
    const float s0 = (float)shift[2 * n];      // along i (columns)
    const float s1 = (float)shift[2 * n + 1];  // along j (rows)
    const float R  = 91.0f / 83.0f;
    const int t    = threadIdx.x;

    const size_t pbase = ((size_t)n * 9 + c0) * NPLANE;
    const float* __restrict__ src = x   + pbase;
    float*       __restrict__ dst = out + pbase;

    const int lane = t & 63;
    const int wv   = t >> 6;               // 0..7
    const int jq   = lane % 21;
    const int isub = lane / 21;            // 0..2 active, 3 idle

    // ---- hoisted y-params (slot-weight form) ----
    float wy0s[4], wy1s[4];
    int   rr[4];
    #pragma unroll
    for (int e = 0; e < 4; ++e) {
        float fy = fmaf((float)(4 * jq + e), R, s1);
        int   y0 = (int)fy;
        float w1 = fy - (float)y0;
        float w0 = 1.0f - w1;
        int   t0 = y0 - 4;
        int   cb = iclamp(t0, 0, HW - 2);
        wy0s[e] = (t0 == cb) ? w0 : ((t0 + 1 == cb) ? w1 : 0.0f);
        wy1s[e] = (t0 == cb) ? w1 : ((t0 - 1 == cb) ? w0 : 0.0f);
        rr[e] = cb;
    }

    // ---- hoisted x-params per sweep k (i = k*24 + wv*3 + isub) ----
    float wx0h[4], wx1h[4];
    int   cu0h[4];
    bool  iok[4];
    #pragma unroll
    for (int k = 0; k < 4; ++k) {
        int i  = k * 24 + wv * 3 + isub;
        iok[k] = (isub < 3) && (i < HW);
        float fx = fmaf((float)i, R, s0);
        int   x0 = (int)fx;
        float w1 = fx - (float)x0;
        float w0 = 1.0f - w1;
        int   u0 = x0 - 4;
        int   cb = iclamp(u0, 0, HW - 2);
        wx0h[k] = (u0 == cb) ? w0 : ((u0 + 1 == cb) ? w1 : 0.0f);
        wx1h[k] = (u0 == cb) ? w1 : ((u0 - 1 == cb) ? w0 : 0.0f);
        cu0h[k] = cb * LDSW;
    }

    // ---- staging helpers (quads q = t, t+512, t+1024, t+1536) ----
    auto loadp = [&](int p, vfloat4& a0, vfloat4& a1, vfloat4& a2, vfloat4& a3) {
        const float* s = src + (size_t)p * NPLANE;
        a0 = *reinterpret_cast<const vfloat4*>(s + 4 * t);
        a1 = *reinterpret_cast<const vfloat4*>(s + 4 * (t + 512));
        a2 = *reinterpret_cast<const vfloat4*>(s + 4 * (t + 1024));
        if (t < NQUADS - 1536)
            a3 = *reinterpret_cast<const vfloat4*>(s + 4 * (t + 1536));
    };
    auto put1 = [&](float* buf, int q, vfloat4 v) {
        int row  = q / 21;
        int col0 = (q - row * 21) * 4;
        int b    = col0 * LDSW + row;
        buf[b]            = v.x;
        buf[b + LDSW]     = v.y;
        buf[b + 2 * LDSW] = v.z;
        buf[b + 3 * LDSW] = v.w;
    };
    auto writep = [&](float* buf, vfloat4 a0, vfloat4 a1, vfloat4 a2, vfloat4 a3) {
        put1(buf, t,        a0);
        put1(buf, t + 512,  a1);
        put1(buf, t + 1024, a2);
        if (t < NQUADS - 1536) put1(buf, t + 1536, a3);
    };
    auto computep = [&](int p, const float* buf) {
        float* d = dst + (size_t)p * NPLANE;
        #pragma unroll
        for (int k = 0; k < 4; ++k) {
            if (iok[k]) {
                int i = k * 24 + wv * 3 + isub;
                vfloat4 o;
                #pragma unroll
                for (int e = 0; e < 4; ++e) {
                    int   b0 = cu0h[k] + rr[e];       // col cb,   rows rr,rr+1
                    int   b1 = b0 + LDSW;             // col cb+1
                    o[e] = wx0h[k] * fmaf(wy0s[e], buf[b0], wy1s[e] * buf[b0 + 1])
                         + wx1h[k] * fmaf(wy0s[e], buf[b1], wy1s[e] * buf[b1 + 1]);
                }
                __builtin_nontemporal_store(
                    o, reinterpret_cast<vfloat4*>(d + (size_t)i * HW + 4 * jq));
            }
        }
    };

    // ---- pipeline: stage 0; {load p+1 | compute p | write p+1 | barrier} ----
    vfloat4 a0, a1, a2, a3;
    loadp(0, a0, a1, a2, a3);
    writep(&lds[0][0], a0, a1, a2, a3);
    __syncthreads();

    #pragma unroll
    for (int p = 0; p < 3; ++p) {
        vfloat4 b0, b1, b2, b3;
        if (p < 2) loadp(p + 1, b0, b1, b2, b3);   // in flight under compute
        computep(p, &lds[p & 1][0]);
        if (p < 2) {
            writep(&lds[(p + 1) & 1][0], b0, b1, b2, b3);
            __syncthreads();
        }
    }
}

extern "C" void kernel_launch(void* const* d_in, const int* in_sizes, int n_in,
                              void* d_out, int out_size, void* d_ws, size_t ws_size,
                              hipStream_t stream) {
    const float* x     = (const float*)d_in[0];
    const int*   shift = (const int*)d_in[1];
    float*       out   = (float*)d_out;
    const int blocks = 512 * 3;        // 3 planes per block
    rshift_kernel<<<blocks, 512, 0, stream>>>(x, shift, out);
}